// Round 5
// baseline (31.616 us; speedup 1.0000x reference)
//
#include <hip/hip_runtime.h>
#include <math.h>

#define HH   512
#define WW   512
#define KG   256
#define NPAIR (KG / 2)
#define NPIX (HH * WW)
#define EPSF 1e-6f
#define LOG2E 1.4426950408889634f

typedef float v2f __attribute__((ext_vector_type(2)));

// Per-pair coefficient block: 20 floats (80 B), pair p covers gaussians 2p,2p+1.
//   [0..1]  ca01   [2..3]  cb01   [4..5]  cc01   [6..7]  cd01
//   [8..9]  ce01   [10..11]cf01   [12..13]c0_01  [14..15]c1_01
//   [16..17]c2_01  [18..19]pad
// log2(w_k(x,y)) = ca*x^2 + cb*y^2 + cc*xy + cd*x + ce*y + cf  (log2e folded)

__global__ __launch_bounds__(KG) void gauss_precompute(
    const float* __restrict__ mu,            // (K,2)
    const float* __restrict__ log_scales,    // (K,2)
    const float* __restrict__ theta,         // (K,)
    const float* __restrict__ color_logits,  // (K,3)
    const float* __restrict__ log_amp,       // (K,1)
    float* __restrict__ params)              // (NPAIR, 20)
{
    const int k = threadIdx.x;
    const int p = k >> 1;
    const int h = k & 1;

    const float mx  = mu[2 * k + 0];
    const float my  = mu[2 * k + 1];
    const float sx  = expf(log_scales[2 * k + 0]);
    const float sy  = expf(log_scales[2 * k + 1]);
    const float isx = 1.0f / (sx * sx + EPSF);
    const float isy = 1.0f / (sy * sy + EPSF);
    const float t   = theta[k];
    const float c   = cosf(t);
    const float s   = sinf(t);

    const float A = c * c * isx + s * s * isy;
    const float B = s * s * isx + c * c * isy;
    const float C = 2.0f * c * s * (isx - isy);

    const float la  = log_amp[k];
    const float amp = (la > 20.0f) ? la : log1pf(expf(la));  // softplus
    const float lnA = logf(amp);

    const float ca = -0.5f * LOG2E * A;
    const float cb = -0.5f * LOG2E * B;
    const float cc = -0.5f * LOG2E * C;
    const float cd = LOG2E * (A * mx + 0.5f * C * my);
    const float ce = LOG2E * (B * my + 0.5f * C * mx);
    const float cf = LOG2E * (lnA - 0.5f * (A * mx * mx + B * my * my + C * mx * my));

    const float c0 = 1.0f / (1.0f + expf(-color_logits[3 * k + 0]));
    const float c1 = 1.0f / (1.0f + expf(-color_logits[3 * k + 1]));
    const float c2 = 1.0f / (1.0f + expf(-color_logits[3 * k + 2]));

    float* base = params + p * 20;
    base[0 + h]  = ca;  base[2 + h]  = cb;
    base[4 + h]  = cc;  base[6 + h]  = cd;
    base[8 + h]  = ce;  base[10 + h] = cf;
    base[12 + h] = c0;  base[14 + h] = c1;
    base[16 + h] = c2;  base[18 + h] = 0.0f;
}

// Render: 1 pixel/thread, loop over 128 gaussian-PAIRS.
// Coefficients read with loop-uniform index -> s_load (scalar pipe, no LDS,
// no vector-mem in the loop). Math packed 2-gaussians-wide -> v_pk_fma_f32.
__global__ __launch_bounds__(256, 4) void gauss_render(
    const float* __restrict__ grid,          // (H,W,2)
    const float* __restrict__ params,        // (NPAIR, 20)
    float* __restrict__ out)                 // (H,W,3)
{
    const int pix = blockIdx.x * 256 + threadIdx.x;

    const float2 gp = reinterpret_cast<const float2*>(grid)[pix];
    const float X = gp.x, Y = gp.y;

    const v2f Xv  = { X, X };
    const v2f Yv  = { Y, Y };
    const v2f X2v = { X * X, X * X };
    const v2f Y2v = { Y * Y, Y * Y };
    const v2f XYv = { X * Y, X * Y };

    v2f den = { 0.f, 0.f };
    v2f R   = { 0.f, 0.f };
    v2f G   = { 0.f, 0.f };
    v2f B   = { 0.f, 0.f };

    #pragma unroll 4
    for (int p = 0; p < NPAIR; ++p) {
        const float4* q = reinterpret_cast<const float4*>(params + p * 20);
        const float4 A4 = q[0];                       // ca01 cb01
        const float4 B4 = q[1];                       // cc01 cd01
        const float4 C4 = q[2];                       // ce01 cf01
        const float4 D4 = q[3];                       // c0_01 c1_01
        const float2 E2 = *reinterpret_cast<const float2*>(q + 4);  // c2_01

        const v2f ca = { A4.x, A4.y }, cb = { A4.z, A4.w };
        const v2f cc = { B4.x, B4.y }, cd = { B4.z, B4.w };
        const v2f ce = { C4.x, C4.y }, cf = { C4.z, C4.w };
        const v2f k0 = { D4.x, D4.y }, k1 = { D4.z, D4.w };
        const v2f k2 = { E2.x, E2.y };

        v2f e = __builtin_elementwise_fma(ce, Yv, cf);
        e = __builtin_elementwise_fma(cd, Xv,  e);
        e = __builtin_elementwise_fma(cc, XYv, e);
        e = __builtin_elementwise_fma(cb, Y2v, e);
        e = __builtin_elementwise_fma(ca, X2v, e);

        v2f w;
        w.x = __builtin_amdgcn_exp2f(e.x);
        w.y = __builtin_amdgcn_exp2f(e.y);

        den += w;
        R = __builtin_elementwise_fma(w, k0, R);
        G = __builtin_elementwise_fma(w, k1, G);
        B = __builtin_elementwise_fma(w, k2, B);
    }

    const float d   = den.x + den.y;
    const float inv = 1.0f / (d + EPSF);
    const float r   = (R.x + R.y) * inv;
    const float g   = (G.x + G.y) * inv;
    const float b   = (B.x + B.y) * inv;

    out[3 * pix + 0] = fminf(fmaxf(r, 0.f), 1.f);
    out[3 * pix + 1] = fminf(fmaxf(g, 0.f), 1.f);
    out[3 * pix + 2] = fminf(fmaxf(b, 0.f), 1.f);
}

extern "C" void kernel_launch(void* const* d_in, const int* in_sizes, int n_in,
                              void* d_out, int out_size, void* d_ws, size_t ws_size,
                              hipStream_t stream) {
    const float* grid         = (const float*)d_in[0];
    const float* mu           = (const float*)d_in[1];
    const float* log_scales   = (const float*)d_in[2];
    const float* theta        = (const float*)d_in[3];
    const float* color_logits = (const float*)d_in[4];
    const float* log_amp      = (const float*)d_in[5];
    float* out    = (float*)d_out;
    float* params = (float*)d_ws;                 // 128 * 80 B = 10 KiB

    hipLaunchKernelGGL(gauss_precompute, dim3(1), dim3(KG), 0, stream,
                       mu, log_scales, theta, color_logits, log_amp, params);

    const int threads = 256;
    const int blocks  = NPIX / threads;           // 1024 blocks, 1 px/thread
    hipLaunchKernelGGL(gauss_render, dim3(blocks), dim3(threads), 0, stream,
                       grid, params, out);
}